// Round 1
// baseline (3707.739 us; speedup 1.0000x reference)
//
#include <hip/hip_runtime.h>
#include <math.h>

// Problem constants (B,T,C)=(4,4096,1024), 16 heads x 64, window 256, rope base 1e4.
#define T_SEQ 4096
#define CDIM  1024
#define HDIM  64
#define WIN   256

// log2(10000)/32 — inv_freq[i] = 2^(-i * this), i = pair index 0..31
#define ROPE_C 0.415241012f

// ---------------------------------------------------------------------------
// GEMM: C[M x N] = A[M x K](lda) @ B[K x N](ldb) + bias[N], row-major fp32.
// 64x64 tile per block, 256 threads, 4x4 acc per thread, K-chunk 16.
// ---------------------------------------------------------------------------
__global__ __launch_bounds__(256)
void gemm_bias_kernel(const float* __restrict__ A, int lda,
                      const float* __restrict__ Bm, int ldb,
                      const float* __restrict__ bias,
                      float* __restrict__ Cm, int ldc, int K) {
  __shared__ float As[16][68];   // [k][row], +4 pad: 2-way conflicts only
  __shared__ float Bs[16][68];   // [k][col]
  const int tx = threadIdx.x, ty = threadIdx.y;
  const int tid = ty * 16 + tx;
  const int row0 = blockIdx.y * 64, col0 = blockIdx.x * 64;
  const int arow = tid >> 2;          // 0..63
  const int akq  = (tid & 3) << 2;    // 0,4,8,12
  const int brow = tid >> 4;          // 0..15
  const int bcol = (tid & 15) << 2;   // 0..60
  const float* Aptr = A + (size_t)(row0 + arow) * lda + akq;
  const float* Bptr = Bm + (size_t)brow * ldb + col0 + bcol;
  float acc[4][4] = {};
  for (int k0 = 0; k0 < K; k0 += 16) {
    float4 av = *(const float4*)(Aptr + k0);
    float4 bv = *(const float4*)(Bptr + (size_t)k0 * ldb);
    As[akq + 0][arow] = av.x;
    As[akq + 1][arow] = av.y;
    As[akq + 2][arow] = av.z;
    As[akq + 3][arow] = av.w;
    *(float4*)&Bs[brow][bcol] = bv;
    __syncthreads();
#pragma unroll
    for (int kk = 0; kk < 16; ++kk) {
      float4 a = *(const float4*)&As[kk][ty << 2];
      float4 b = *(const float4*)&Bs[kk][tx << 2];
      acc[0][0] = fmaf(a.x, b.x, acc[0][0]);
      acc[0][1] = fmaf(a.x, b.y, acc[0][1]);
      acc[0][2] = fmaf(a.x, b.z, acc[0][2]);
      acc[0][3] = fmaf(a.x, b.w, acc[0][3]);
      acc[1][0] = fmaf(a.y, b.x, acc[1][0]);
      acc[1][1] = fmaf(a.y, b.y, acc[1][1]);
      acc[1][2] = fmaf(a.y, b.z, acc[1][2]);
      acc[1][3] = fmaf(a.y, b.w, acc[1][3]);
      acc[2][0] = fmaf(a.z, b.x, acc[2][0]);
      acc[2][1] = fmaf(a.z, b.y, acc[2][1]);
      acc[2][2] = fmaf(a.z, b.z, acc[2][2]);
      acc[2][3] = fmaf(a.z, b.w, acc[2][3]);
      acc[3][0] = fmaf(a.w, b.x, acc[3][0]);
      acc[3][1] = fmaf(a.w, b.y, acc[3][1]);
      acc[3][2] = fmaf(a.w, b.z, acc[3][2]);
      acc[3][3] = fmaf(a.w, b.w, acc[3][3]);
    }
    __syncthreads();
  }
  float4 bb = *(const float4*)&bias[col0 + (tx << 2)];
#pragma unroll
  for (int i = 0; i < 4; ++i) {
    float4 o;
    o.x = acc[i][0] + bb.x;
    o.y = acc[i][1] + bb.y;
    o.z = acc[i][2] + bb.z;
    o.w = acc[i][3] + bb.w;
    *(float4*)&Cm[(size_t)(row0 + (ty << 2) + i) * ldc + col0 + (tx << 2)] = o;
  }
}

// ---------------------------------------------------------------------------
// Windowed attention. One block per (window, head, batch). 256 threads,
// thread i = query row i of the window. K/V staged in LDS 128 rows at a
// time (64 KiB total -> 2 blocks/CU). RoPE applied on load (abs position).
// Two-pass online softmax; output written IN-PLACE over the q slot of qkv
// (safe: each thread reads its own q row into regs before any y write, and
// no other block reads this (b,h,window) q region; k/v slots never written).
// ---------------------------------------------------------------------------
__device__ __forceinline__ void stage_kv(const float* __restrict__ qkv,
                                         int b, int t0, int cch, int h,
                                         int krow, int pair0,
                                         float (*Ks)[64], float (*Vs)[64]) {
  const int tr = t0 + cch * 128 + krow;
  const float* kp = qkv + ((size_t)b * T_SEQ + tr) * (3 * CDIM) + CDIM + h * HDIM;
  const float* vp = kp + CDIM;
  const float tf = (float)tr;
#pragma unroll
  for (int i = 0; i < 16; ++i) {
    int pi = pair0 + i;                         // pair index 0..31
    float inv = exp2f(-(float)pi * ROPE_C);
    float ang = tf * inv;
    float sa = sinf(ang), ca = cosf(ang);
    float x1 = kp[2 * pi], x2 = kp[2 * pi + 1];
    Ks[krow][2 * pi]     = fmaf(x1, ca, -x2 * sa);
    Ks[krow][2 * pi + 1] = fmaf(x1, sa,  x2 * ca);
  }
#pragma unroll
  for (int i4 = 0; i4 < 8; ++i4) {
    ((float4*)&Vs[krow][pair0 * 2])[i4] = ((const float4*)(vp + pair0 * 2))[i4];
  }
}

__global__ __launch_bounds__(256)
void attn_kernel(float* __restrict__ qkv) {
  __shared__ float Ks[128][64];   // 32 KiB
  __shared__ float Vs[128][64];   // 32 KiB
  const int w = blockIdx.x, h = blockIdx.y, b = blockIdx.z;
  const int tid = threadIdx.x;            // query row within window
  const int t0 = w * WIN;
  const int t  = t0 + tid;
  const size_t rowbase = ((size_t)b * T_SEQ + t) * (3 * CDIM);
  const float* qp = qkv + rowbase + h * HDIM;

  // Load own q row with RoPE into registers.
  float q[64];
#pragma unroll
  for (int i = 0; i < 32; ++i) {
    float inv = exp2f(-(float)i * ROPE_C);
    float ang = (float)t * inv;
    float sa = sinf(ang), ca = cosf(ang);
    float x1 = qp[2 * i], x2 = qp[2 * i + 1];
    q[2 * i]     = fmaf(x1, ca, -x2 * sa);
    q[2 * i + 1] = fmaf(x1, sa,  x2 * ca);
  }

  const int krow  = tid >> 1;         // 0..127: row this thread stages
  const int pair0 = (tid & 1) * 16;   // which half of the 32 rope pairs

  // Pass 1: running max m and denominator l over all 256 keys.
  float m = -1e30f, l = 0.f;
  for (int cch = 0; cch < 2; ++cch) {
    stage_kv(qkv, b, t0, cch, h, krow, pair0, Ks, Vs);
    __syncthreads();
#pragma unroll 4
    for (int j = 0; j < 128; ++j) {
      const float4* kr = (const float4*)Ks[j];
      float s = 0.f;
#pragma unroll
      for (int d4 = 0; d4 < 16; ++d4) {
        float4 kk = kr[d4];
        s = fmaf(q[4 * d4 + 0], kk.x, s);
        s = fmaf(q[4 * d4 + 1], kk.y, s);
        s = fmaf(q[4 * d4 + 2], kk.z, s);
        s = fmaf(q[4 * d4 + 3], kk.w, s);
      }
      s *= 0.125f;
      float mn = fmaxf(m, s);
      l = l * __expf(m - mn) + __expf(s - mn);
      m = mn;
    }
    __syncthreads();
  }

  // Pass 2: recompute scores, accumulate y = sum p_j * V[j].
  float y[64] = {};
  for (int cch = 0; cch < 2; ++cch) {
    stage_kv(qkv, b, t0, cch, h, krow, pair0, Ks, Vs);
    __syncthreads();
#pragma unroll 4
    for (int j = 0; j < 128; ++j) {
      const float4* kr = (const float4*)Ks[j];
      float s = 0.f;
#pragma unroll
      for (int d4 = 0; d4 < 16; ++d4) {
        float4 kk = kr[d4];
        s = fmaf(q[4 * d4 + 0], kk.x, s);
        s = fmaf(q[4 * d4 + 1], kk.y, s);
        s = fmaf(q[4 * d4 + 2], kk.z, s);
        s = fmaf(q[4 * d4 + 3], kk.w, s);
      }
      float p = __expf(s * 0.125f - m);
      const float4* vr = (const float4*)Vs[j];
#pragma unroll
      for (int d4 = 0; d4 < 16; ++d4) {
        float4 vv = vr[d4];
        y[4 * d4 + 0] = fmaf(p, vv.x, y[4 * d4 + 0]);
        y[4 * d4 + 1] = fmaf(p, vv.y, y[4 * d4 + 1]);
        y[4 * d4 + 2] = fmaf(p, vv.z, y[4 * d4 + 2]);
        y[4 * d4 + 3] = fmaf(p, vv.w, y[4 * d4 + 3]);
      }
    }
    __syncthreads();
  }

  const float rl = 1.f / l;
  float* yp = qkv + rowbase + h * HDIM;   // overwrite q slot with y
#pragma unroll
  for (int d4 = 0; d4 < 16; ++d4) {
    float4 o;
    o.x = y[4 * d4 + 0] * rl;
    o.y = y[4 * d4 + 1] * rl;
    o.z = y[4 * d4 + 2] * rl;
    o.w = y[4 * d4 + 3] * rl;
    ((float4*)yp)[d4] = o;
  }
}

// ---------------------------------------------------------------------------
// ws layout: qkv fp32 [B*T, 3C] = 192 MiB at offset 0. Attention output y is
// written in-place over the q third of qkv; out-GEMM reads it with lda=3072.
// ---------------------------------------------------------------------------
extern "C" void kernel_launch(void* const* d_in, const int* in_sizes, int n_in,
                              void* d_out, int out_size, void* d_ws, size_t ws_size,
                              hipStream_t stream) {
  const float* x     = (const float*)d_in[0];
  const float* W_in  = (const float*)d_in[1];
  const float* b_in  = (const float*)d_in[2];
  const float* W_out = (const float*)d_in[3];
  const float* b_out = (const float*)d_in[4];
  float* out = (float*)d_out;
  float* qkv = (float*)d_ws;

  dim3 blk(16, 16);
  // qkv = x @ W_in + b_in : [16384 x 3072], K=1024
  gemm_bias_kernel<<<dim3(3072 / 64, 16384 / 64), blk, 0, stream>>>(
      x, CDIM, W_in, 3 * CDIM, b_in, qkv, 3 * CDIM, CDIM);
  // windowed attention, y in-place over q slots
  attn_kernel<<<dim3(T_SEQ / WIN, 16, 4), 256, 0, stream>>>(qkv);
  // out = y @ W_out + b_out : [16384 x 1024], K=1024, A has lda=3072
  gemm_bias_kernel<<<dim3(CDIM / 64, 16384 / 64), blk, 0, stream>>>(
      qkv, 3 * CDIM, W_out, CDIM, b_out, out, CDIM, CDIM);
}